// Round 2
// baseline (518.869 us; speedup 1.0000x reference)
//
#include <hip/hip_runtime.h>

// ACELoss3D round 12: R10 main kernel (verified 119.7us) + counter-based
// last-block finalization replacing the ace_final dispatch.
// R11 post-mortem: hipLaunchCooperativeKernel silently no-ops under the
// harness's graph capture (out[0] stayed 0 => absmax == |ref|). Cooperative
// grid.sync is unusable here. Instead: each block release-fences its partials
// and bumps a device-scope atomic counter; the last block re-reduces the
// 3x6144 partials with agent-scope atomic loads (coherence-point reads, so no
// stale per-XCD L2 poison lines) and writes out[0]. Counter is zero-inited by
// a 4-byte memset node (~1us) replacing the ~5us 1-block second dispatch.
// History: R6 XCD swizzle neutral; R7 8-elem regressed; R8 sched_barrier
// +1.5us; R9 4x4 tile +3.5us; R10 wave y-exchange 119.7us (main ~30us; 2x41us
// harness poison fills are fixed overhead); R11 cooperative fuse FAILED.

static constexpr int   NTOT   = 6 * 128 * 128 * 128;   // 12,582,912
static constexpr int   NBLK   = 6144;                  // 32x32 xy-tiles * 6 bc
static constexpr float ALPHA_ = 0.001f;
static constexpr float MIU_   = 1.0f;
static constexpr float EPS_   = 1e-8f;

__device__ __forceinline__ void wave_reduce3(float& a, float& b, float& c) {
#pragma unroll
  for (int off = 32; off > 0; off >>= 1) {
    a += __shfl_down(a, off);
    b += __shfl_down(b, off);
    c += __shfl_down(c, off);
  }
}

// One output element. di/dj = un-halved first diffs; sx/sy = uxp+uxm, uyp+uym;
// dik/djk/dij = un-halved mixed double-diffs. 2*cik*cjk*cij = 0.25*dik*djk*dij.
__device__ __forceinline__ void elem(
    float uzm, float u0, float uzp,
    float di, float sx, float dj, float sy,
    float dik, float djk, float dij,
    float t, float& s1, float& s2, float& s3) {
  const float dk  = uzp - uzm;
  const float ci2 = 0.25f * di * di;
  const float cj2 = 0.25f * dj * dj;
  const float ck2 = 0.25f * dk * dk;
  const float u2  = u0 + u0;
  const float cii = sx - u2;
  const float cjj = sy - u2;
  const float ckk = (uzp + uzm) - u2;
  const float ss  = ci2 + cj2 + ck2;
  const float ss1 = 1.f + ss;
  const float L = (cii + cjj) + ckk;
  const float M = fmaf(ci2, cii, fmaf(cj2, cjj, ck2 * ckk));
  float curv = fmaf(ss1, L, -M);
  curv = fmaf(-0.25f * dij, dik * djk, curv);
  const float len = __builtin_amdgcn_sqrtf(EPS_ + ss);
  s3 = fmaf(curv * curv, len * __builtin_amdgcn_rcpf(ss1), s3);
  const float tm1 = t - 1.f;
  s1 = fmaf(u0, tm1 * tm1, s1);
  s2 = fmaf(1.f - u0, t * t, s2);
}

__global__ __launch_bounds__(512, 4) void ace_main(
    const float* __restrict__ pred, const float* __restrict__ truth,
    float* __restrict__ partials, int* __restrict__ counter,
    float* __restrict__ out) {
  const int tid = threadIdx.x;
  // Block -> (bc, y-tile, x-tile); thread -> (x-sub, y-sub, z-group).
  const int rem = blockIdx.x & 1023;        // 32x32 xy tiles
  const int bc  = blockIdx.x >> 10;         // 0..5
  const int x   = ((rem & 31) << 2)  + (tid >> 7);
  const int y   = ((rem >> 5) << 2)  + ((tid >> 5) & 3);
  const int z0  = (tid & 31) << 2;                         // 0,4,...,124
  const size_t base = ((size_t)bc) << 21;
  const float* __restrict__ bp = pred + base;

  // Wave halves: lanes 0-31 = even y-sub, lanes 32-63 = odd y-sub (adjacent y).
  const bool upper = (tid & 32) != 0;
  const float sgn  = upper ? 1.f : -1.f;
  const int yOut = upper ? ((y < 127) ? y + 1 : 127) : ((y > 0) ? y - 1 : 0);
  const int rO  = yOut << 7;
  const int rC  = y << 7;
  const int pC  = x << 14;
  const int pXp = ((x < 127) ? x + 1 : 127) << 14;
  const int pXm = ((x > 0)   ? x - 1 : 0)   << 14;

  // 7 float4 loads (was 10) — all pinned in flight before any consumer.
  const float4 vC  = *(const float4*)(bp + pC  + rC + z0);
  const float4 vXP = *(const float4*)(bp + pXp + rC + z0);
  const float4 vXM = *(const float4*)(bp + pXm + rC + z0);
  const float4 vOY = *(const float4*)(bp + pC  + rO + z0);   // outward y row
  const float4 vOP = *(const float4*)(bp + pXp + rO + z0);
  const float4 vOM = *(const float4*)(bp + pXm + rO + z0);
  const float4 t4  = *(const float4*)(truth + base + pC + rC + z0);
#if defined(__has_builtin)
#if __has_builtin(__builtin_amdgcn_sched_barrier)
  __builtin_amdgcn_sched_barrier(0);   // keep all 7 loads issued before math
#endif
#endif

  // Center-row x combines.
  const float dxa = vXP.x - vXM.x, dxb = vXP.y - vXM.y;
  const float dxc = vXP.z - vXM.z, dxd = vXP.w - vXM.w;
  const float sxa = vXP.x + vXM.x, sxb = vXP.y + vXM.y;
  const float sxc = vXP.z + vXM.z, sxd = vXP.w + vXM.w;
  // Outward-row x-diff.
  const float dOa = vOP.x - vOM.x, dOb = vOP.y - vOM.y;
  const float dOc = vOP.z - vOM.z, dOd = vOP.w - vOM.w;

  // Inward y-neighbor via half-wave exchange (partner row is never clamped).
  const float iCa = __shfl_xor(vC.x, 32), iCb = __shfl_xor(vC.y, 32);
  const float iCc = __shfl_xor(vC.z, 32), iCd = __shfl_xor(vC.w, 32);
  const float iDa = __shfl_xor(dxa, 32),  iDb = __shfl_xor(dxb, 32);
  const float iDc = __shfl_xor(dxc, 32),  iDd = __shfl_xor(dxd, 32);

  // y combines: sy order-free; dy/j get the half sign.
  const float sya = iCa + vOY.x, syb = iCb + vOY.y;
  const float syc = iCc + vOY.z, syd = iCd + vOY.w;
  const float dya = sgn * (vOY.x - iCa), dyb = sgn * (vOY.y - iCb);
  const float dyc = sgn * (vOY.z - iCc), dyd = sgn * (vOY.w - iCd);
  const float ja  = sgn * (dOa - iDa),   jb  = sgn * (dOb - iDb);
  const float jc  = sgn * (dOc - iDc),   jd  = sgn * (dOd - iDd);

  // z-halo from adjacent lanes (lane i-1 holds z0-4..z0-1). Clamp lanes
  // (tid&31)==0 / ==31 are select-overridden, so the +-1 shuffles never leak
  // across the 32-lane z-line boundary (where y changes).
  const bool zlo = (z0 == 0), zhi = (z0 == 124);
  float clo  = __shfl_up  (vC.w, 1);  clo  = zlo ? vC.x : clo;
  float chi  = __shfl_down(vC.x, 1);  chi  = zhi ? vC.w : chi;
  float dxm1 = __shfl_up  (dxd, 1);   dxm1 = zlo ? dxa : dxm1;
  float dxp4 = __shfl_down(dxa, 1);   dxp4 = zhi ? dxd : dxp4;
  float dym1 = __shfl_up  (dyd, 1);   dym1 = zlo ? dya : dym1;
  float dyp4 = __shfl_down(dya, 1);   dyp4 = zhi ? dyd : dyp4;

  float s1 = 0.f, s2 = 0.f, s3 = 0.f;
  elem(clo,  vC.x, vC.y, dxa, sxa, dya, sya, dxb - dxm1, dyb - dym1, ja, t4.x, s1, s2, s3);
  elem(vC.x, vC.y, vC.z, dxb, sxb, dyb, syb, dxc - dxa,  dyc - dya,  jb, t4.y, s1, s2, s3);
  elem(vC.y, vC.z, vC.w, dxc, sxc, dyc, syc, dxd - dxb,  dyd - dyb,  jc, t4.z, s1, s2, s3);
  elem(vC.z, vC.w, chi,  dxd, sxd, dyd, syd, dxp4 - dxc, dyp4 - dyc, jd, t4.w, s1, s2, s3);

  wave_reduce3(s1, s2, s3);
  __shared__ float l1[8], l2[8], l3[8];
  __shared__ bool amLast;
  const int lane = tid & 63, wv = tid >> 6;
  if (lane == 0) { l1[wv] = s1; l2[wv] = s2; l3[wv] = s3; }
  __syncthreads();
  if (tid == 0) {
    float p1 = 0.f, p2 = 0.f, p3 = 0.f;
#pragma unroll
    for (int w = 0; w < 8; ++w) { p1 += l1[w]; p2 += l2[w]; p3 += l3[w]; }
    partials[blockIdx.x]            = p1;
    partials[NBLK + blockIdx.x]     = p2;
    partials[2 * NBLK + blockIdx.x] = p3;
    // Release: partials stores must be globally visible before the counter
    // bump. Device-scope fence + agent-scope atomic (coherence point) are
    // valid across non-coherent per-XCD L2s.
    __threadfence();
    const int old = __hip_atomic_fetch_add(counter, 1, __ATOMIC_ACQ_REL,
                                           __HIP_MEMORY_SCOPE_AGENT);
    amLast = (old == NBLK - 1);
  }
  __syncthreads();
  if (!amLast) return;

  // Last block: reduce 3*NBLK partials. Agent-scope atomic loads read at the
  // coherence point — immune to stale poison lines in this XCD's L2.
  __threadfence();
  float a = 0.f, b = 0.f, c = 0.f;
#pragma unroll
  for (int it = 0; it < NBLK / 512; ++it) {
    const int i = it * 512 + tid;
    a += __hip_atomic_load(&partials[i],            __ATOMIC_RELAXED,
                           __HIP_MEMORY_SCOPE_AGENT);
    b += __hip_atomic_load(&partials[NBLK + i],     __ATOMIC_RELAXED,
                           __HIP_MEMORY_SCOPE_AGENT);
    c += __hip_atomic_load(&partials[2 * NBLK + i], __ATOMIC_RELAXED,
                           __HIP_MEMORY_SCOPE_AGENT);
  }
  wave_reduce3(a, b, c);
  // l1..l3 reuse is safe: their phase-1 reads (tid 0) happened before the
  // __syncthreads above.
  if (lane == 0) { l1[wv] = a; l2[wv] = b; l3[wv] = c; }
  __syncthreads();
  if (tid == 0) {
    float S1 = 0.f, S2 = 0.f, S3 = 0.f;
#pragma unroll
    for (int w = 0; w < 8; ++w) { S1 += l1[w]; S2 += l2[w]; S3 += l3[w]; }
    out[0] = MIU_ * fabsf(S1) + fabsf(S2) + S3 + ALPHA_ * (float)NTOT;
  }
}

extern "C" void kernel_launch(void* const* d_in, const int* in_sizes, int n_in,
                              void* d_out, int out_size, void* d_ws, size_t ws_size,
                              hipStream_t stream) {
  const float* pred  = (const float*)d_in[0];   // y_pred
  const float* truth = (const float*)d_in[1];   // y_true
  float* out      = (float*)d_out;
  float* partials = (float*)d_ws;               // 3*NBLK floats = 73.7 KB
  // Counter lives past the partials, on its own cache line.
  int* counter = (int*)((char*)d_ws + ((3 * NBLK * 4 + 255) & ~255));

  hipMemsetAsync(counter, 0, sizeof(int), stream);   // graph-capturable node
  ace_main<<<NBLK, 512, 0, stream>>>(pred, truth, partials, counter, out);
}

// Round 3
// 175.394 us; speedup vs baseline: 2.9583x; 2.9583x over previous
//
#include <hip/hip_runtime.h>

// ACELoss3D round 13: R10 main kernel (verified ~32us) + fenceless fusion of
// the final reduction via one relaxed device-scope atomicAdd per block.
// Key identity: s1 = sum u*(t-1)^2 and s2 = sum (1-u)*t^2 are sums of
// non-negative terms (u,t in [0,1)), so the reference's abs() is a no-op and
// out = MIU*S1 + S2 + S3 + ALPHA*NTOT is a PLAIN SUM -> order-free atomics.
// R12 post-mortem: per-block agent-scope fence+ACQ_REL atomic = XCD L2
// writeback/invalidate per block -> 440us (13x). Plain atomicAdd emits no
// cache maintenance; 6144 fire-and-forget f32 atomics are free.
// out[0] zero-init via our own 4B memset node (graph-safe, keeps replays
// correct); block 0 contributes the ALPHA*NTOT constant.
// History: R6 XCD swizzle neutral; R7 8-elem regressed; R8 sched_barrier
// +1.5us; R9 4x4 tile +3.5us; R10 two-kernel 119.7us (main ~32us, final ~5us,
// 2x41us harness poison fills fixed); R11 cooperative FAILED (no-op under
// graph capture); R12 fence catastrophe 518.9us.

static constexpr int   NTOT   = 6 * 128 * 128 * 128;   // 12,582,912
static constexpr int   NBLK   = 6144;                  // 32x32 xy-tiles * 6 bc
static constexpr float ALPHA_ = 0.001f;
static constexpr float MIU_   = 1.0f;
static constexpr float EPS_   = 1e-8f;

__device__ __forceinline__ void wave_reduce3(float& a, float& b, float& c) {
#pragma unroll
  for (int off = 32; off > 0; off >>= 1) {
    a += __shfl_down(a, off);
    b += __shfl_down(b, off);
    c += __shfl_down(c, off);
  }
}

// One output element. di/dj = un-halved first diffs; sx/sy = uxp+uxm, uyp+uym;
// dik/djk/dij = un-halved mixed double-diffs. 2*cik*cjk*cij = 0.25*dik*djk*dij.
__device__ __forceinline__ void elem(
    float uzm, float u0, float uzp,
    float di, float sx, float dj, float sy,
    float dik, float djk, float dij,
    float t, float& s1, float& s2, float& s3) {
  const float dk  = uzp - uzm;
  const float ci2 = 0.25f * di * di;
  const float cj2 = 0.25f * dj * dj;
  const float ck2 = 0.25f * dk * dk;
  const float u2  = u0 + u0;
  const float cii = sx - u2;
  const float cjj = sy - u2;
  const float ckk = (uzp + uzm) - u2;
  const float ss  = ci2 + cj2 + ck2;
  const float ss1 = 1.f + ss;
  const float L = (cii + cjj) + ckk;
  const float M = fmaf(ci2, cii, fmaf(cj2, cjj, ck2 * ckk));
  float curv = fmaf(ss1, L, -M);
  curv = fmaf(-0.25f * dij, dik * djk, curv);
  const float len = __builtin_amdgcn_sqrtf(EPS_ + ss);
  s3 = fmaf(curv * curv, len * __builtin_amdgcn_rcpf(ss1), s3);
  const float tm1 = t - 1.f;
  s1 = fmaf(u0, tm1 * tm1, s1);
  s2 = fmaf(1.f - u0, t * t, s2);
}

__global__ __launch_bounds__(512, 4) void ace_main(
    const float* __restrict__ pred, const float* __restrict__ truth,
    float* __restrict__ out) {
  const int tid = threadIdx.x;
  // Block -> (bc, y-tile, x-tile); thread -> (x-sub, y-sub, z-group).
  const int rem = blockIdx.x & 1023;        // 32x32 xy tiles
  const int bc  = blockIdx.x >> 10;         // 0..5
  const int x   = ((rem & 31) << 2)  + (tid >> 7);
  const int y   = ((rem >> 5) << 2)  + ((tid >> 5) & 3);
  const int z0  = (tid & 31) << 2;                         // 0,4,...,124
  const size_t base = ((size_t)bc) << 21;
  const float* __restrict__ bp = pred + base;

  // Wave halves: lanes 0-31 = even y-sub, lanes 32-63 = odd y-sub (adjacent y).
  const bool upper = (tid & 32) != 0;
  const float sgn  = upper ? 1.f : -1.f;
  const int yOut = upper ? ((y < 127) ? y + 1 : 127) : ((y > 0) ? y - 1 : 0);
  const int rO  = yOut << 7;
  const int rC  = y << 7;
  const int pC  = x << 14;
  const int pXp = ((x < 127) ? x + 1 : 127) << 14;
  const int pXm = ((x > 0)   ? x - 1 : 0)   << 14;

  // 7 float4 loads (was 10) — all pinned in flight before any consumer.
  const float4 vC  = *(const float4*)(bp + pC  + rC + z0);
  const float4 vXP = *(const float4*)(bp + pXp + rC + z0);
  const float4 vXM = *(const float4*)(bp + pXm + rC + z0);
  const float4 vOY = *(const float4*)(bp + pC  + rO + z0);   // outward y row
  const float4 vOP = *(const float4*)(bp + pXp + rO + z0);
  const float4 vOM = *(const float4*)(bp + pXm + rO + z0);
  const float4 t4  = *(const float4*)(truth + base + pC + rC + z0);
#if defined(__has_builtin)
#if __has_builtin(__builtin_amdgcn_sched_barrier)
  __builtin_amdgcn_sched_barrier(0);   // keep all 7 loads issued before math
#endif
#endif

  // Center-row x combines.
  const float dxa = vXP.x - vXM.x, dxb = vXP.y - vXM.y;
  const float dxc = vXP.z - vXM.z, dxd = vXP.w - vXM.w;
  const float sxa = vXP.x + vXM.x, sxb = vXP.y + vXM.y;
  const float sxc = vXP.z + vXM.z, sxd = vXP.w + vXM.w;
  // Outward-row x-diff.
  const float dOa = vOP.x - vOM.x, dOb = vOP.y - vOM.y;
  const float dOc = vOP.z - vOM.z, dOd = vOP.w - vOM.w;

  // Inward y-neighbor via half-wave exchange (partner row is never clamped).
  const float iCa = __shfl_xor(vC.x, 32), iCb = __shfl_xor(vC.y, 32);
  const float iCc = __shfl_xor(vC.z, 32), iCd = __shfl_xor(vC.w, 32);
  const float iDa = __shfl_xor(dxa, 32),  iDb = __shfl_xor(dxb, 32);
  const float iDc = __shfl_xor(dxc, 32),  iDd = __shfl_xor(dxd, 32);

  // y combines: sy order-free; dy/j get the half sign.
  const float sya = iCa + vOY.x, syb = iCb + vOY.y;
  const float syc = iCc + vOY.z, syd = iCd + vOY.w;
  const float dya = sgn * (vOY.x - iCa), dyb = sgn * (vOY.y - iCb);
  const float dyc = sgn * (vOY.z - iCc), dyd = sgn * (vOY.w - iCd);
  const float ja  = sgn * (dOa - iDa),   jb  = sgn * (dOb - iDb);
  const float jc  = sgn * (dOc - iDc),   jd  = sgn * (dOd - iDd);

  // z-halo from adjacent lanes (lane i-1 holds z0-4..z0-1). Clamp lanes
  // (tid&31)==0 / ==31 are select-overridden, so the +-1 shuffles never leak
  // across the 32-lane z-line boundary (where y changes).
  const bool zlo = (z0 == 0), zhi = (z0 == 124);
  float clo  = __shfl_up  (vC.w, 1);  clo  = zlo ? vC.x : clo;
  float chi  = __shfl_down(vC.x, 1);  chi  = zhi ? vC.w : chi;
  float dxm1 = __shfl_up  (dxd, 1);   dxm1 = zlo ? dxa : dxm1;
  float dxp4 = __shfl_down(dxa, 1);   dxp4 = zhi ? dxd : dxp4;
  float dym1 = __shfl_up  (dyd, 1);   dym1 = zlo ? dya : dym1;
  float dyp4 = __shfl_down(dya, 1);   dyp4 = zhi ? dyd : dyp4;

  float s1 = 0.f, s2 = 0.f, s3 = 0.f;
  elem(clo,  vC.x, vC.y, dxa, sxa, dya, sya, dxb - dxm1, dyb - dym1, ja, t4.x, s1, s2, s3);
  elem(vC.x, vC.y, vC.z, dxb, sxb, dyb, syb, dxc - dxa,  dyc - dya,  jb, t4.y, s1, s2, s3);
  elem(vC.y, vC.z, vC.w, dxc, sxc, dyc, syc, dxd - dxb,  dyd - dyb,  jc, t4.z, s1, s2, s3);
  elem(vC.z, vC.w, chi,  dxd, sxd, dyd, syd, dxp4 - dxc, dyp4 - dyc, jd, t4.w, s1, s2, s3);

  wave_reduce3(s1, s2, s3);
  __shared__ float l1[8], l2[8], l3[8];
  const int lane = tid & 63, wv = tid >> 6;
  if (lane == 0) { l1[wv] = s1; l2[wv] = s2; l3[wv] = s3; }
  __syncthreads();
  if (tid == 0) {
    float p1 = 0.f, p2 = 0.f, p3 = 0.f;
#pragma unroll
    for (int w = 0; w < 8; ++w) { p1 += l1[w]; p2 += l2[w]; p3 += l3[w]; }
    // abs(S1)/abs(S2) are no-ops (non-negative terms) -> the whole result is
    // a plain sum -> one relaxed device-scope f32 atomic per block. No fence,
    // no cache-maintenance (R12 lesson). Block 0 carries the constant.
    float v = fmaf(MIU_, p1, p2 + p3);
    if (blockIdx.x == 0) v += ALPHA_ * (float)NTOT;
    atomicAdd(out, v);
  }
}

extern "C" void kernel_launch(void* const* d_in, const int* in_sizes, int n_in,
                              void* d_out, int out_size, void* d_ws, size_t ws_size,
                              hipStream_t stream) {
  const float* pred  = (const float*)d_in[0];   // y_pred
  const float* truth = (const float*)d_in[1];   // y_true
  float* out = (float*)d_out;

  hipMemsetAsync(out, 0, sizeof(float), stream);   // own the zero-init
  ace_main<<<NBLK, 512, 0, stream>>>(pred, truth, out);
}

// Round 4
// 125.549 us; speedup vs baseline: 4.1328x; 1.3970x over previous
//
#include <hip/hip_runtime.h>

// ACELoss3D round 14: single kernel, grid 1024 (one xy-tile per block, loop
// over 6 bc channels in registers), ONE relaxed atomicAdd per block.
// R13 post-mortem: 6144 single-address f32 atomics serialized at the
// coherence point (~9ns each => +55us; hbm 9%, VALU 26% -> not BW/compute).
// 1024 atomics => <=9us worst-case, staggered by bc-loop timing variance.
// Loop body is bit-identical to verified R10/R13; offsets loop-invariant.
// Identity (verified R13, absmax 0.0): S1,S2 are sums of non-negative terms,
// abs() is a no-op, result is a plain sum -> order-free atomic accumulation.
// History: R10 two-kernel 119.7us (main ~30us latency-bound: 61MB HBM fetch
// @2TB/s, rest L3; 2x41us harness ws-poison fills are fixed overhead);
// R11 cooperative launch no-ops under graph capture; R12 agent-scope fence
// per block = XCD L2 maintenance catastrophe (518us); R13 atomic contention.

static constexpr int   NTOT   = 6 * 128 * 128 * 128;   // 12,582,912
static constexpr int   GRID   = 1024;                  // 32x32 xy-tiles
static constexpr float ALPHA_ = 0.001f;
static constexpr float MIU_   = 1.0f;
static constexpr float EPS_   = 1e-8f;

__device__ __forceinline__ void wave_reduce3(float& a, float& b, float& c) {
#pragma unroll
  for (int off = 32; off > 0; off >>= 1) {
    a += __shfl_down(a, off);
    b += __shfl_down(b, off);
    c += __shfl_down(c, off);
  }
}

// One output element. di/dj = un-halved first diffs; sx/sy = uxp+uxm, uyp+uym;
// dik/djk/dij = un-halved mixed double-diffs. 2*cik*cjk*cij = 0.25*dik*djk*dij.
__device__ __forceinline__ void elem(
    float uzm, float u0, float uzp,
    float di, float sx, float dj, float sy,
    float dik, float djk, float dij,
    float t, float& s1, float& s2, float& s3) {
  const float dk  = uzp - uzm;
  const float ci2 = 0.25f * di * di;
  const float cj2 = 0.25f * dj * dj;
  const float ck2 = 0.25f * dk * dk;
  const float u2  = u0 + u0;
  const float cii = sx - u2;
  const float cjj = sy - u2;
  const float ckk = (uzp + uzm) - u2;
  const float ss  = ci2 + cj2 + ck2;
  const float ss1 = 1.f + ss;
  const float L = (cii + cjj) + ckk;
  const float M = fmaf(ci2, cii, fmaf(cj2, cjj, ck2 * ckk));
  float curv = fmaf(ss1, L, -M);
  curv = fmaf(-0.25f * dij, dik * djk, curv);
  const float len = __builtin_amdgcn_sqrtf(EPS_ + ss);
  s3 = fmaf(curv * curv, len * __builtin_amdgcn_rcpf(ss1), s3);
  const float tm1 = t - 1.f;
  s1 = fmaf(u0, tm1 * tm1, s1);
  s2 = fmaf(1.f - u0, t * t, s2);
}

__global__ __launch_bounds__(512, 4) void ace_main(
    const float* __restrict__ pred, const float* __restrict__ truth,
    float* __restrict__ out) {
  const int tid = threadIdx.x;
  // Block = one 4x4x128 xy-tile; thread -> (x-sub, y-sub, z-group).
  const int rem = blockIdx.x;               // 0..1023: 32x32 xy tiles
  const int x   = ((rem & 31) << 2)  + (tid >> 7);
  const int y   = ((rem >> 5) << 2)  + ((tid >> 5) & 3);
  const int z0  = (tid & 31) << 2;                         // 0,4,...,124

  // Wave halves: lanes 0-31 = even y-sub, lanes 32-63 = odd y-sub (adjacent y).
  const bool upper = (tid & 32) != 0;
  const float sgn  = upper ? 1.f : -1.f;
  const int yOut = upper ? ((y < 127) ? y + 1 : 127) : ((y > 0) ? y - 1 : 0);
  const int rO  = yOut << 7;
  const int rC  = y << 7;
  const int pC  = x << 14;
  const int pXp = ((x < 127) ? x + 1 : 127) << 14;
  const int pXm = ((x > 0)   ? x - 1 : 0)   << 14;
  // Loop-invariant element offsets (bc advances the base pointer only).
  const int iC  = pC  + rC + z0;
  const int iXP = pXp + rC + z0;
  const int iXM = pXm + rC + z0;
  const int iOY = pC  + rO + z0;
  const int iOP = pXp + rO + z0;
  const int iOM = pXm + rO + z0;
  const bool zlo = (z0 == 0), zhi = (z0 == 124);

  float s1 = 0.f, s2 = 0.f, s3 = 0.f;
  const float* __restrict__ bp = pred;
  const float* __restrict__ bt = truth;

#pragma unroll 1
  for (int bc = 0; bc < 6; ++bc) {
    // 7 float4 loads — all pinned in flight before any consumer.
    const float4 vC  = *(const float4*)(bp + iC);
    const float4 vXP = *(const float4*)(bp + iXP);
    const float4 vXM = *(const float4*)(bp + iXM);
    const float4 vOY = *(const float4*)(bp + iOY);   // outward y row
    const float4 vOP = *(const float4*)(bp + iOP);
    const float4 vOM = *(const float4*)(bp + iOM);
    const float4 t4  = *(const float4*)(bt + iC);
    bp += 1 << 21;
    bt += 1 << 21;
#if defined(__has_builtin)
#if __has_builtin(__builtin_amdgcn_sched_barrier)
    __builtin_amdgcn_sched_barrier(0);   // keep all 7 loads issued before math
#endif
#endif

    // Center-row x combines.
    const float dxa = vXP.x - vXM.x, dxb = vXP.y - vXM.y;
    const float dxc = vXP.z - vXM.z, dxd = vXP.w - vXM.w;
    const float sxa = vXP.x + vXM.x, sxb = vXP.y + vXM.y;
    const float sxc = vXP.z + vXM.z, sxd = vXP.w + vXM.w;
    // Outward-row x-diff.
    const float dOa = vOP.x - vOM.x, dOb = vOP.y - vOM.y;
    const float dOc = vOP.z - vOM.z, dOd = vOP.w - vOM.w;

    // Inward y-neighbor via half-wave exchange (partner row never clamped).
    const float iCa = __shfl_xor(vC.x, 32), iCb = __shfl_xor(vC.y, 32);
    const float iCc = __shfl_xor(vC.z, 32), iCd = __shfl_xor(vC.w, 32);
    const float iDa = __shfl_xor(dxa, 32),  iDb = __shfl_xor(dxb, 32);
    const float iDc = __shfl_xor(dxc, 32),  iDd = __shfl_xor(dxd, 32);

    // y combines: sy order-free; dy/j get the half sign.
    const float sya = iCa + vOY.x, syb = iCb + vOY.y;
    const float syc = iCc + vOY.z, syd = iCd + vOY.w;
    const float dya = sgn * (vOY.x - iCa), dyb = sgn * (vOY.y - iCb);
    const float dyc = sgn * (vOY.z - iCc), dyd = sgn * (vOY.w - iCd);
    const float ja  = sgn * (dOa - iDa),   jb  = sgn * (dOb - iDb);
    const float jc  = sgn * (dOc - iDc),   jd  = sgn * (dOd - iDd);

    // z-halo from adjacent lanes; clamp lanes select-overridden so the +-1
    // shuffles never leak across the 32-lane z-line boundary.
    float clo  = __shfl_up  (vC.w, 1);  clo  = zlo ? vC.x : clo;
    float chi  = __shfl_down(vC.x, 1);  chi  = zhi ? vC.w : chi;
    float dxm1 = __shfl_up  (dxd, 1);   dxm1 = zlo ? dxa : dxm1;
    float dxp4 = __shfl_down(dxa, 1);   dxp4 = zhi ? dxd : dxp4;
    float dym1 = __shfl_up  (dyd, 1);   dym1 = zlo ? dya : dym1;
    float dyp4 = __shfl_down(dya, 1);   dyp4 = zhi ? dyd : dyp4;

    elem(clo,  vC.x, vC.y, dxa, sxa, dya, sya, dxb - dxm1, dyb - dym1, ja, t4.x, s1, s2, s3);
    elem(vC.x, vC.y, vC.z, dxb, sxb, dyb, syb, dxc - dxa,  dyc - dya,  jb, t4.y, s1, s2, s3);
    elem(vC.y, vC.z, vC.w, dxc, sxc, dyc, syc, dxd - dxb,  dyd - dyb,  jc, t4.z, s1, s2, s3);
    elem(vC.z, vC.w, chi,  dxd, sxd, dyd, syd, dxp4 - dxc, dyp4 - dyc, jd, t4.w, s1, s2, s3);
  }

  // One reduction + ONE atomic for all 6 channels (1024 total, was 6144).
  wave_reduce3(s1, s2, s3);
  __shared__ float l1[8], l2[8], l3[8];
  const int lane = tid & 63, wv = tid >> 6;
  if (lane == 0) { l1[wv] = s1; l2[wv] = s2; l3[wv] = s3; }
  __syncthreads();
  if (tid == 0) {
    float p1 = 0.f, p2 = 0.f, p3 = 0.f;
#pragma unroll
    for (int w = 0; w < 8; ++w) { p1 += l1[w]; p2 += l2[w]; p3 += l3[w]; }
    float v = fmaf(MIU_, p1, p2 + p3);
    if (blockIdx.x == 0) v += ALPHA_ * (float)NTOT;
    atomicAdd(out, v);   // relaxed, device-scope, no fence (R12/R13 lessons)
  }
}

extern "C" void kernel_launch(void* const* d_in, const int* in_sizes, int n_in,
                              void* d_out, int out_size, void* d_ws, size_t ws_size,
                              hipStream_t stream) {
  const float* pred  = (const float*)d_in[0];   // y_pred
  const float* truth = (const float*)d_in[1];   // y_true
  float* out = (float*)d_out;

  hipMemsetAsync(out, 0, sizeof(float), stream);   // own the zero-init
  ace_main<<<GRID, 512, 0, stream>>>(pred, truth, out);
}